// Round 20
// baseline (226.659 us; speedup 1.0000x reference)
//
#include <hip/hip_runtime.h>

#define B_  2
#define T_  2048
#define C_  1024
#define H_  16
#define HS_ 64
#define FF_ 4096
#define BT_ 4096
#define LDQKV 3072

typedef __bf16 bf16x8 __attribute__((ext_vector_type(8)));
typedef float f32x4 __attribute__((ext_vector_type(4)));

// Native f32->bf16 (RNE, single hardware cvt)
__device__ __forceinline__ unsigned short f2bf(float f) {
    union { __bf16 h; unsigned short u; } cv;
    cv.h = (__bf16)f;
    return cv.u;
}
__device__ __forceinline__ float bf2f(unsigned short b) {
    return __uint_as_float(((unsigned int)b) << 16);
}
// raw 2^x (v_exp_f32)
__device__ __forceinline__ float fexp2(float x) {
    float r;
    asm("v_exp_f32 %0, %1" : "=v"(r) : "v"(x));
    return r;
}
#define EXP_SCALE 0.18033688011112042f   // 0.125 * log2(e)

__device__ __forceinline__ void gload16(const void* g, void* l) {
    __builtin_amdgcn_global_load_lds(
        (const __attribute__((address_space(1))) void*)g,
        (__attribute__((address_space(3))) void*)l, 16, 0, 0);
}

// ---------------------------------------------------------------------------
// Unified preprocessing: ONE launch does x->bf16 convert + all 4 weight
// transposes (segment-mapped flat grid; segments are block-uniform).
// ---------------------------------------------------------------------------
__global__ __launch_bounds__(256) void prep_all(
    const float* __restrict__ x,
    const float* __restrict__ wq, const float* __restrict__ wk,
    const float* __restrict__ wv, const float* __restrict__ wproj,
    const float* __restrict__ w1, const float* __restrict__ w2,
    unsigned short* __restrict__ xb, unsigned short* __restrict__ wqkvt,
    unsigned short* __restrict__ wprojt, unsigned short* __restrict__ w1t,
    unsigned short* __restrict__ w2t)
{
    int bid = blockIdx.x;
    if (bid < 4096) {                       // x convert
        int i = bid * 256 + threadIdx.x;
        float4 v = ((const float4*)x)[i];
        ushort4 o;
        o.x = f2bf(v.x); o.y = f2bf(v.y); o.z = f2bf(v.z); o.w = f2bf(v.w);
        ((ushort4*)xb)[i] = o;
        return;
    }
    bid -= 4096;

    const float* in; int ldb; long b_os;
    unsigned short* outp; int K; int bx, by;
    if (bid < 3072) {                       // wq/wk/wv
        int wsel = bid >> 10, r = bid & 1023;
        in = (wsel == 0) ? wq : (wsel == 1) ? wk : wv;
        ldb = HS_; b_os = (long)C_ * HS_;
        outp = wqkvt + (long)wsel * C_ * C_;
        K = C_; bx = r & 31; by = r >> 5;
    } else if (bid < 4096) {                // wproj
        int r = bid - 3072;
        in = wproj; ldb = C_; b_os = 64L;
        outp = wprojt; K = C_; bx = r & 31; by = r >> 5;
    } else if (bid < 8192) {                // w1
        int r = bid - 4096;
        in = w1; ldb = FF_; b_os = 64L;
        outp = w1t; K = C_; bx = r & 31; by = r >> 5;
    } else {                                // w2
        int r = bid - 8192;
        in = w2; ldb = C_; b_os = 64L;
        outp = w2t; K = FF_; bx = r & 127; by = r >> 7;
    }

    __shared__ float t[32][33];
    const int k0 = bx * 32, n0 = by * 32;
    const int tx = threadIdx.x & 31, ty = threadIdx.x >> 5;
    #pragma unroll
    for (int i = 0; i < 4; i++) {
        int k = k0 + ty + i * 8;
        int n = n0 + tx;
        t[ty + i * 8][tx] = in[(long)(n >> 6) * b_os + (long)k * ldb + (n & 63)];
    }
    __syncthreads();
    #pragma unroll
    for (int i = 0; i < 4; i++) {
        int n = n0 + ty + i * 8;
        outp[(long)n * K + k0 + tx] = f2bf(t[tx][ty + i * 8]);
    }
}

// ---------------------------------------------------------------------------
// bf16 MFMA GEMM (2-phase dbuf, XCD supertile swizzle). proj split-K=4.
// ---------------------------------------------------------------------------
template<bool RELU, bool BIAS, bool OUT_BF16>
__global__ __launch_bounds__(256) void gemm_mfma(
    const unsigned short* __restrict__ A, int lda,
    const unsigned short* __restrict__ Bt, int ldb,
    void* __restrict__ Cc, const float* __restrict__ bias,
    int M, int N, int Ksub)
{
    __shared__ __align__(16) unsigned short As[2][128 * 32];
    __shared__ __align__(16) unsigned short Bs[2][128 * 32];
    const int tid = threadIdx.x;
    const int w = tid >> 6, l = tid & 63;
    const int fr = l & 15, fq = l >> 4;

    const int gx = gridDim.x;
    const int total = gx * gridDim.y;
    const int bid = blockIdx.y * gx + blockIdx.x;
    const int v = (bid & 7) * (total >> 3) + (bid >> 3);
    const int sw8 = gx << 3;
    const int r = v % sw8;
    const int mt = ((v / sw8) << 3) + (r & 7);
    const int nt = r >> 3;
    const int m0 = mt * 128, n0 = nt * 128;

    const int wm = (w >> 1) * 64, wn = (w & 1) * 64;
    const int kz = blockIdx.z;
    A  += (long)kz * Ksub;
    Bt += (long)kz * Ksub;

    f32x4 acc[4][4];
    #pragma unroll
    for (int m = 0; m < 4; m++)
        #pragma unroll
        for (int n = 0; n < 4; n++) acc[m][n] = (f32x4){0.f, 0.f, 0.f, 0.f};

    const int s0 = w * 64 + l;
    const int s1 = 256 + s0;
    const int nkt = Ksub >> 5;

    {
        gload16(&A[(long)(m0 + (s0 >> 2)) * lda + (s0 & 3) * 8], &As[0][s0 * 8]);
        gload16(&Bt[(long)(n0 + (s0 >> 2)) * ldb + (s0 & 3) * 8], &Bs[0][s0 * 8]);
        gload16(&A[(long)(m0 + (s1 >> 2)) * lda + (s1 & 3) * 8], &As[0][s1 * 8]);
        gload16(&Bt[(long)(n0 + (s1 >> 2)) * ldb + (s1 & 3) * 8], &Bs[0][s1 * 8]);
    }
    __syncthreads();

    for (int kt = 0; kt < nkt; kt++) {
        const int cur = kt & 1;
        const int nxt = cur ^ 1;

        if (kt + 1 < nkt) {
            const int k0 = (kt + 1) * 32;
            gload16(&A[(long)(m0 + (s0 >> 2)) * lda + k0 + (s0 & 3) * 8], &As[nxt][s0 * 8]);
            gload16(&Bt[(long)(n0 + (s0 >> 2)) * ldb + k0 + (s0 & 3) * 8], &Bs[nxt][s0 * 8]);
            gload16(&A[(long)(m0 + (s1 >> 2)) * lda + k0 + (s1 & 3) * 8], &As[nxt][s1 * 8]);
            gload16(&Bt[(long)(n0 + (s1 >> 2)) * ldb + k0 + (s1 & 3) * 8], &Bs[nxt][s1 * 8]);
        }

        bf16x8 a[4], b[4];
        #pragma unroll
        for (int m = 0; m < 4; m++)
            a[m] = *(const bf16x8*)&As[cur][(wm + m * 16 + fr) * 32 + fq * 8];
        #pragma unroll
        for (int n = 0; n < 4; n++)
            b[n] = *(const bf16x8*)&Bs[cur][(wn + n * 16 + fr) * 32 + fq * 8];
        __builtin_amdgcn_s_setprio(1);
        #pragma unroll
        for (int m = 0; m < 4; m++)
            #pragma unroll
            for (int n = 0; n < 4; n++)
                acc[m][n] = __builtin_amdgcn_mfma_f32_16x16x32_bf16(
                    a[m], b[n], acc[m][n], 0, 0, 0);
        __builtin_amdgcn_s_setprio(0);

        __syncthreads();
    }

    const long obase = (long)kz * M * N;
    #pragma unroll
    for (int m = 0; m < 4; m++) {
        #pragma unroll
        for (int n = 0; n < 4; n++) {
            int col = n0 + wn + n * 16 + fr;
            float bv = BIAS ? bias[col] : 0.f;
            #pragma unroll
            for (int j = 0; j < 4; j++) {
                long row = m0 + wm + m * 16 + fq * 4 + j;
                float v2 = acc[m][n][j] + bv;
                if (RELU) v2 = fmaxf(v2, 0.f);
                if (OUT_BF16) ((unsigned short*)Cc)[obase + row * N + col] = f2bf(v2);
                else          ((float*)Cc)[obase + row * N + col] = v2;
            }
        }
    }
}

// ---------------------------------------------------------------------------
// 256x256 8-phase GEMM (T2+T3+T4 template) with KSPLIT split-K.
// ---------------------------------------------------------------------------
template<bool RELU, bool BIAS, int KSPLIT>
__global__ __launch_bounds__(512) void gemm256_8ph(
    const unsigned short* __restrict__ A, int lda,
    const unsigned short* __restrict__ Bt, int ldb,
    unsigned short* __restrict__ Cc, const float* __restrict__ bias,
    int M, int N, int Ksub)
{
    __shared__ __align__(16) unsigned short As[2][2][256 * 32];
    __shared__ __align__(16) unsigned short Bs[2][2][256 * 32];
    const int tid = threadIdx.x;
    const int w = tid >> 6, l = tid & 63;
    const int fr = l & 15, fq = l >> 4;
    const int rl = l >> 2, sg = l & 3;
    const int swl = (sg ^ ((rl >> 1) & 3)) * 8;   // pre-swizzled k-offset

    const int ntn = N >> 8;
    const int ntiles = (M >> 8) * ntn;
    const int total = ntiles * KSPLIT;
    const int bid = blockIdx.x;
    const int v = (bid & 7) * (total >> 3) + (bid >> 3);
    const int kz = v / ntiles;
    const int tl = v % ntiles;
    const int mt = tl / ntn, nt = tl % ntn;
    const int m0 = mt << 8, n0 = nt << 8;
    A  += (long)kz * Ksub;
    Bt += (long)kz * Ksub;

    const int wrow = (w >> 2) * 128;
    const int wcol = (w & 3) * 64;

    f32x4 acc[8][4];
    #pragma unroll
    for (int m = 0; m < 8; m++)
        #pragma unroll
        for (int n = 0; n < 4; n++) acc[m][n] = (f32x4){0.f, 0.f, 0.f, 0.f};

    const int nkt = Ksub >> 6;   // K-tiles of 64 (>= 2)

#define STG256(P_, ld_, rb0_, blk_, t_, kk_) do {                             \
        _Pragma("unroll")                                                     \
        for (int i_ = 0; i_ < 2; i_++) {                                      \
            int u_ = w + i_ * 8;                                              \
            int R_ = u_ * 16 + rl;                                            \
            gload16(&(P_)[(long)((rb0_) + R_) * (ld_) + (t_) * 64 + (kk_) * 32 + swl], \
                    &(blk_)[u_ * 512 + l * 8]);                               \
        }                                                                     \
    } while (0)

#define PHASE256(d_, kk_, mh_) do {                                           \
        bf16x8 a_[4], b_[4];                                                  \
        _Pragma("unroll")                                                     \
        for (int m_ = 0; m_ < 4; m_++) {                                      \
            int R_ = wrow + (mh_) * 64 + m_ * 16 + fr;                        \
            a_[m_] = *(const bf16x8*)&As[d_][kk_][R_ * 32 + (fq ^ ((R_ >> 1) & 3)) * 8]; \
        }                                                                     \
        _Pragma("unroll")                                                     \
        for (int n_ = 0; n_ < 4; n_++) {                                      \
            int R_ = wcol + n_ * 16 + fr;                                     \
            b_[n_] = *(const bf16x8*)&Bs[d_][kk_][R_ * 32 + (fq ^ ((R_ >> 1) & 3)) * 8]; \
        }                                                                     \
        __builtin_amdgcn_s_setprio(1);                                        \
        _Pragma("unroll")                                                     \
        for (int m_ = 0; m_ < 4; m_++)                                        \
            _Pragma("unroll")                                                 \
            for (int n_ = 0; n_ < 4; n_++)                                    \
                acc[(mh_) * 4 + m_][n_] = __builtin_amdgcn_mfma_f32_16x16x32_bf16( \
                    a_[m_], b_[n_], acc[(mh_) * 4 + m_][n_], 0, 0, 0);        \
        __builtin_amdgcn_s_setprio(0);                                        \
    } while (0)

    STG256(A, lda, m0, As[0][0], 0, 0);
    STG256(Bt, ldb, n0, Bs[0][0], 0, 0);
    STG256(A, lda, m0, As[0][1], 0, 1);
    STG256(Bt, ldb, n0, Bs[0][1], 0, 1);
    STG256(A, lda, m0, As[1][0], 1, 0);
    STG256(Bt, ldb, n0, Bs[1][0], 1, 0);
    asm volatile("s_waitcnt vmcnt(8)" ::: "memory");
    __builtin_amdgcn_s_barrier();

    for (int t = 0; t < nkt; t++) {
        const int d = t & 1;

        if (t + 1 < nkt) STG256(A, lda, m0, As[d ^ 1][1], t + 1, 1);
        PHASE256(d, 0, 0);
        if (t + 1 < nkt) STG256(Bt, ldb, n0, Bs[d ^ 1][1], t + 1, 1);
        PHASE256(d, 0, 1);

        if (t + 1 < nkt) asm volatile("s_waitcnt vmcnt(8)" ::: "memory");
        else             asm volatile("s_waitcnt vmcnt(0)" ::: "memory");
        __builtin_amdgcn_s_barrier();

        if (t + 2 < nkt) STG256(A, lda, m0, As[d][0], t + 2, 0);
        PHASE256(d, 1, 0);
        if (t + 2 < nkt) STG256(Bt, ldb, n0, Bs[d][0], t + 2, 0);
        PHASE256(d, 1, 1);

        if (t + 1 < nkt) {
            if (t + 2 < nkt) asm volatile("s_waitcnt vmcnt(8)" ::: "memory");
            else             asm volatile("s_waitcnt vmcnt(4)" ::: "memory");
            __builtin_amdgcn_s_barrier();
        }
    }
#undef STG256
#undef PHASE256

    const long obase = (long)kz * M * N;
    #pragma unroll
    for (int mi = 0; mi < 8; mi++) {
        #pragma unroll
        for (int n = 0; n < 4; n++) {
            int col = n0 + wcol + n * 16 + fr;
            float bv = BIAS ? bias[col] : 0.f;
            #pragma unroll
            for (int j = 0; j < 4; j++) {
                long row = m0 + wrow + (mi >> 2) * 64 + (mi & 3) * 16 + fq * 4 + j;
                float vv = acc[mi][n][j] + bv;
                if (RELU) vv = fmaxf(vv, 0.f);
                Cc[obase + row * N + col] = f2bf(vv);
            }
        }
    }
}

// ---------------------------------------------------------------------------
// MFMA flash attention, round 20: split-KV (z halves) with trivial merge.
// Max-free softmax makes partials ADDITIVE: block (b,h,qt,z) computes
// unnormalized O = sum p*v and l = sum p over its KV sub-range
//   z=0: st in [0, qt+1)     z=1: st in [qt+1, 2qt+2)
// Grid 1024 (was 512) -> 3 blocks/CU resident (LDS 53.2KB x 3 fits).
// CU-complementary quadrant decode: per-CU work = 34 tiles exactly.
// Partial O -> bf16 buffers Ob[z]; l -> f32 L[z][row][h]; merged by
// attn_merge: out = (O0+O1)/(l0+l1).
// ---------------------------------------------------------------------------
__global__ __launch_bounds__(512) void attn_mfma(
    const unsigned short* __restrict__ qkv,
    unsigned short* __restrict__ ob0, unsigned short* __restrict__ ob1,
    float* __restrict__ l0p, float* __restrict__ l1p)
{
    const int bid = blockIdx.x;           // 0..1023
    const int u   = bid & 255;
    const int q2  = bid >> 8;             // quadrant 0..3
    const int h   = u & 15;
    const int j4  = u >> 4;               // 0..15
    int b, qt, z;
    if (q2 == 0)      { b = 0; qt = j4;      z = 0; }
    else if (q2 == 1) { b = 0; qt = 15 - j4; z = 1; }
    else if (q2 == 2) { b = 1; qt = j4;      z = 1; }
    else              { b = 1; qt = 15 - j4; z = 0; }
    const int st0 = z ? (qt + 1) : 0;
    const int st1 = z ? (2 * qt + 2) : (qt + 1);
    unsigned short* ob = z ? ob1 : ob0;
    float* Lp = z ? l1p : l0p;

    const int tid = threadIdx.x;
    const int w = tid >> 6, l = tid & 63;
    const int fr = l & 15, fq = l >> 4;

    __shared__ __align__(16) unsigned short Ks[2][64 * 64];
    __shared__ __align__(16) unsigned short Vt[2][64 * 72];
    __shared__ __align__(16) unsigned short Ps[8][16 * 72];

    const long qrow = (long)(b * T_ + qt * 128 + w * 16 + fr);
    const bf16x8 qf0 = *(const bf16x8*)&qkv[qrow * LDQKV + h * 64 + fq * 8];
    const bf16x8 qf1 = *(const bf16x8*)&qkv[qrow * LDQKV + h * 64 + 32 + fq * 8];

    const bf16x8 ones = {(__bf16)1.f, (__bf16)1.f, (__bf16)1.f, (__bf16)1.f,
                         (__bf16)1.f, (__bf16)1.f, (__bf16)1.f, (__bf16)1.f};

    const int kr  = tid >> 3;
    const int keo = ((tid & 7) ^ (kr & 7)) * 8;
    const int vr  = tid >> 3;
    const int vc  = (tid & 7) * 8;
    const int vrs = vr ^ ((tid & 7) << 3);

    f32x4 oacc[4];
    f32x4 lacc = (f32x4){0.f, 0.f, 0.f, 0.f};
    #pragma unroll
    for (int d = 0; d < 4; d++) oacc[d] = (f32x4){0.f, 0.f, 0.f, 0.f};

    const unsigned short* kb0 = qkv + (long)b * T_ * LDQKV + 1024 + h * 64;
    const unsigned short* vb0 = qkv + (long)b * T_ * LDQKV + 2048 + h * 64;

    const int qminw = qt * 128 + w * 16;
    const int qmaxw = qminw + 15;

    // ---- prologue: stage tile st0 (buffer parity st0&1) ----
    {
        const unsigned short* kb = kb0 + (long)st0 * 64 * LDQKV;
        const unsigned short* vb = vb0 + (long)st0 * 64 * LDQKV;
        gload16(kb + (long)kr * LDQKV + keo, &Ks[st0 & 1][tid * 8]);
        bf16x8 vv = *(const bf16x8*)&vb[(long)vr * LDQKV + vc];
        #pragma unroll
        for (int jj = 0; jj < 8; jj++)
            Vt[st0 & 1][(vc + jj) * 72 + vrs] = ((const unsigned short*)&vv)[jj];
    }
    __syncthreads();

    for (int st = st0; st < st1; st++) {
        const int cur = st & 1;
        const int nxt = cur ^ 1;

        bf16x8 vnext;
        if (st + 1 < st1) {
            const unsigned short* kb = kb0 + (long)(st + 1) * 64 * LDQKV;
            const unsigned short* vb = vb0 + (long)(st + 1) * 64 * LDQKV;
            gload16(kb + (long)kr * LDQKV + keo, &Ks[nxt][tid * 8]);
            vnext = *(const bf16x8*)&vb[(long)vr * LDQKV + vc];
        }

        const int sbase = st * 64;
        if (sbase <= qmaxw) {   // wave-uniform: skip fully-masked tiles
            f32x4 sacc[4];
            {
                bf16x8 k0v[4], k1v[4];
                #pragma unroll
                for (int stile = 0; stile < 4; stile++) {
                    int krow = stile * 16 + fr;
                    int rb = krow * 128;
                    int sw = (krow & 7) << 4;
                    k0v[stile] = *(const bf16x8*)((const char*)Ks[cur] + rb + ((fq * 16) ^ sw));
                    k1v[stile] = *(const bf16x8*)((const char*)Ks[cur] + rb + ((64 + fq * 16) ^ sw));
                }
                __builtin_amdgcn_s_setprio(1);
                #pragma unroll
                for (int stile = 0; stile < 4; stile++) {
                    sacc[stile] = (f32x4){0.f, 0.f, 0.f, 0.f};
                    sacc[stile] = __builtin_amdgcn_mfma_f32_16x16x32_bf16(qf0, k0v[stile], sacc[stile], 0, 0, 0);
                    sacc[stile] = __builtin_amdgcn_mfma_f32_16x16x32_bf16(qf1, k1v[stile], sacc[stile], 0, 0, 0);
                }
                __builtin_amdgcn_s_setprio(0);
            }

            if (sbase + 63 <= qminw) {
                #pragma unroll
                for (int stile = 0; stile < 4; stile++)
                    #pragma unroll
                    for (int j = 0; j < 4; j++)
                        Ps[w][(fq * 4 + j) * 72 + stile * 16 + fr] =
                            f2bf(fexp2(sacc[stile][j] * EXP_SCALE));
            } else {
                const int qbase = qminw + fq * 4;
                #pragma unroll
                for (int stile = 0; stile < 4; stile++) {
                    #pragma unroll
                    for (int j = 0; j < 4; j++) {
                        float e = fexp2(sacc[stile][j] * EXP_SCALE);
                        if (sbase + stile * 16 + fr > qbase + j) e = 0.f;
                        Ps[w][(fq * 4 + j) * 72 + stile * 16 + fr] = f2bf(e);
                    }
                }
            }

            {
                bf16x8 pf0 = *(const bf16x8*)&Ps[w][fr * 72 + fq * 8];
                bf16x8 pf1 = *(const bf16x8*)&Ps[w][fr * 72 + 32 + fq * 8];
                __builtin_amdgcn_s_setprio(1);
                lacc = __builtin_amdgcn_mfma_f32_16x16x32_bf16(pf0, ones, lacc, 0, 0, 0);
                lacc = __builtin_amdgcn_mfma_f32_16x16x32_bf16(pf1, ones, lacc, 0, 0, 0);
                #pragma unroll
                for (int df = 0; df < 4; df++) {
                    int row = df * 16 + fr;
                    int c = (row >> 3) & 7;
                    bf16x8 v0 = *(const bf16x8*)&Vt[cur][row * 72 + ((fq ^ c) * 8)];
                    bf16x8 v1 = *(const bf16x8*)&Vt[cur][row * 72 + (((fq + 4) ^ c) * 8)];
                    oacc[df] = __builtin_amdgcn_mfma_f32_16x16x32_bf16(pf0, v0, oacc[df], 0, 0, 0);
                    oacc[df] = __builtin_amdgcn_mfma_f32_16x16x32_bf16(pf1, v1, oacc[df], 0, 0, 0);
                }
                __builtin_amdgcn_s_setprio(0);
            }
        }

        if (st + 1 < st1) {
            #pragma unroll
            for (int jj = 0; jj < 8; jj++)
                Vt[nxt][(vc + jj) * 72 + vrs] = ((const unsigned short*)&vnext)[jj];
        }

        __syncthreads();
    }

    // ---- epilogue: write UNNORMALIZED partials + l ----
    #pragma unroll
    for (int j = 0; j < 4; j++) {
        long orow = (long)(b * T_ + qt * 128 + w * 16 + fq * 4 + j);
        if (fr == 0) Lp[orow * H_ + h] = lacc[j];
        #pragma unroll
        for (int df = 0; df < 4; df++)
            ob[orow * C_ + h * 64 + df * 16 + fr] = f2bf(oacc[df][j]);
    }
}

// ---------------------------------------------------------------------------
// attn partial merge: O = (O0 + O1) / (l0 + l1), in place into O0.
// ---------------------------------------------------------------------------
__global__ __launch_bounds__(256) void attn_merge(
    unsigned short* __restrict__ O0, const unsigned short* __restrict__ O1,
    const float* __restrict__ L0, const float* __restrict__ L1)
{
    const long row = blockIdx.x;
    const int tid = threadIdx.x;
    const int h = tid >> 4;                 // element base tid*4 -> head
    const float inv = 1.f / (L0[row * H_ + h] + L1[row * H_ + h]);
    ushort4 a = ((const ushort4*)(O0 + row * C_))[tid];
    ushort4 c = ((const ushort4*)(O1 + row * C_))[tid];
    ushort4 o;
    o.x = f2bf((bf2f(a.x) + bf2f(c.x)) * inv);
    o.y = f2bf((bf2f(a.y) + bf2f(c.y)) * inv);
    o.z = f2bf((bf2f(a.z) + bf2f(c.z)) * inv);
    o.w = f2bf((bf2f(a.w) + bf2f(c.w)) * inv);
    ((ushort4*)(O0 + row * C_))[tid] = o;
}

// ---------------------------------------------------------------------------
// Fused residual + NP-partial split-K merge + bias + LayerNorm
// ---------------------------------------------------------------------------
template<bool WB, int NP>
__global__ __launch_bounds__(256) void ln_fused(
    const float* __restrict__ a,
    const unsigned short* __restrict__ b0, const unsigned short* __restrict__ b1,
    const unsigned short* __restrict__ b2p, const unsigned short* __restrict__ b3p,
    const float* __restrict__ bias,
    const float* __restrict__ g, const float* __restrict__ be,
    float* __restrict__ outf, unsigned short* __restrict__ outb)
{
    const long row = blockIdx.x;
    const int tid = threadIdx.x;

    float4 av = ((const float4*)(a + row * C_))[tid];
    ushort4 b0v = ((const ushort4*)(b0 + row * C_))[tid];
    ushort4 b1v = ((const ushort4*)(b1 + row * C_))[tid];
    float4 biv = ((const float4*)bias)[tid];
    float v[4];
    v[0] = av.x + bf2f(b0v.x) + bf2f(b1v.x) + biv.x;
    v[1] = av.y + bf2f(b0v.y) + bf2f(b1v.y) + biv.y;
    v[2] = av.z + bf2f(b0v.z) + bf2f(b1v.z) + biv.z;
    v[3] = av.w + bf2f(b0v.w) + bf2f(b1v.w) + biv.w;
    if (NP == 4) {
        ushort4 b2v = ((const ushort4*)(b2p + row * C_))[tid];
        ushort4 b3v = ((const ushort4*)(b3p + row * C_))[tid];
        v[0] += bf2f(b2v.x) + bf2f(b3v.x);
        v[1] += bf2f(b2v.y) + bf2f(b3v.y);
        v[2] += bf2f(b2v.z) + bf2f(b3v.z);
        v[3] += bf2f(b2v.w) + bf2f(b3v.w);
    }

    float s = v[0] + v[1] + v[2] + v[3];
    #pragma unroll
    for (int off = 32; off > 0; off >>= 1) s += __shfl_down(s, off);
    __shared__ float red[4], red2[4];
    const int wid = tid >> 6, lane = tid & 63;
    if (lane == 0) red[wid] = s;
    __syncthreads();
    float mean = (red[0] + red[1] + red[2] + red[3]) * (1.f / 1024.f);

    float vs = 0.f;
    #pragma unroll
    for (int i = 0; i < 4; i++) { float d = v[i] - mean; vs += d * d; }
    #pragma unroll
    for (int off = 32; off > 0; off >>= 1) vs += __shfl_down(vs, off);
    if (lane == 0) red2[wid] = vs;
    __syncthreads();
    float var = (red2[0] + red2[1] + red2[2] + red2[3]) * (1.f / 1024.f);
    float rstd = rsqrtf(var + 1e-5f);

    float4 gv = ((const float4*)g)[tid];
    float4 ev = ((const float4*)be)[tid];
    float4 ov;
    ov.x = (v[0] - mean) * rstd * gv.x + ev.x;
    ov.y = (v[1] - mean) * rstd * gv.y + ev.y;
    ov.z = (v[2] - mean) * rstd * gv.z + ev.z;
    ov.w = (v[3] - mean) * rstd * gv.w + ev.w;
    ((float4*)(outf + row * C_))[tid] = ov;
    if (WB) {
        ushort4 o;
        o.x = f2bf(ov.x); o.y = f2bf(ov.y); o.z = f2bf(ov.z); o.w = f2bf(ov.w);
        ((ushort4*)(outb + row * C_))[tid] = o;
    }
}

// ---------------------------------------------------------------------------
// Workspace (MB), liveness-packed, peak 96:
//   [0,8)   xb   -> ffP0     [8,14) wqkvt -> ffP1[8,16)
//   [14,16) wprojt           [16,24) w1t -> ffP2
//   [24,32) Ob1 (attn) -> projP0/ffP3
//   [32,56) qkv -> projP1..3 -> hb[32,64)
//   [56,64) attnb (Ob0/merged)
//   [64,72) w2t              [72,88) x1f
//   [88,96) L0/L1 (attn) -> x1b
// ---------------------------------------------------------------------------
extern "C" void kernel_launch(void* const* d_in, const int* in_sizes, int n_in,
                              void* d_out, int out_size, void* d_ws, size_t ws_size,
                              hipStream_t stream) {
    const float* x     = (const float*)d_in[0];
    const float* wq    = (const float*)d_in[1];
    const float* wk    = (const float*)d_in[2];
    const float* wv    = (const float*)d_in[3];
    const float* wproj = (const float*)d_in[4];
    const float* bproj = (const float*)d_in[5];
    const float* ln1g  = (const float*)d_in[6];
    const float* ln1b  = (const float*)d_in[7];
    const float* w1    = (const float*)d_in[8];
    const float* b1    = (const float*)d_in[9];
    const float* w2    = (const float*)d_in[10];
    const float* b2    = (const float*)d_in[11];
    const float* ln2g  = (const float*)d_in[12];
    const float* ln2b  = (const float*)d_in[13];
    float* out = (float*)d_out;

    char* wsb = (char*)d_ws;
    unsigned short* xb     = (unsigned short*)(wsb);                 // [0,8)
    unsigned short* wqkvt  = (unsigned short*)(wsb + (8L  << 20));   // [8,14)
    unsigned short* wprojt = (unsigned short*)(wsb + (14L << 20));   // [14,16)
    unsigned short* w1t    = (unsigned short*)(wsb + (16L << 20));   // [16,24)
    unsigned short* w2t    = (unsigned short*)(wsb + (64L << 20));   // [64,72)
    unsigned short* qkv    = (unsigned short*)(wsb + (32L << 20));   // [32,56)
    unsigned short* attnb  = (unsigned short*)(wsb + (56L << 20));   // [56,64) Ob0
    unsigned short* ob1    = (unsigned short*)(wsb + (24L << 20));   // [24,32)
    float*          l0p    = (float*)(wsb + (88L << 20));            // 256KB
    float*          l1p    = (float*)(wsb + (88L << 20) + (256L << 10));
    unsigned short* projP  = (unsigned short*)(wsb + (24L << 20));   // [24,56)
    float*          x1f    = (float*)(wsb + (72L << 20));            // [72,88)
    unsigned short* x1b    = (unsigned short*)(wsb + (88L << 20));   // [88,96)
    unsigned short* hb     = (unsigned short*)(wsb + (32L << 20));   // [32,64)
    unsigned short* ffP    = (unsigned short*)(wsb);                 // [0,32)

    dim3 blk(256);

    // unified preprocessing: convert + all weight transposes, ONE launch
    prep_all<<<dim3(16384), blk, 0, stream>>>(
        x, wq, wk, wv, wproj, w1, w2, xb, wqkvt, wprojt, w1t, w2t);

    // fused QKV projection: 8-phase 256x256, 192 tiles (N=3072)
    gemm256_8ph<false, false, 1><<<dim3(192), dim3(512), 0, stream>>>(
        xb, C_, wqkvt, C_, qkv, nullptr, BT_, LDQKV, C_);

    // attention: split-KV (1024 blocks, 3/CU resident) + additive merge
    attn_mfma<<<dim3(1024), dim3(512), 0, stream>>>(qkv, attnb, ob1, l0p, l1p);
    attn_merge<<<dim3(BT_), blk, 0, stream>>>(attnb, ob1, l0p, l1p);

    // output projection, 2-phase split-K=4 (bias in LN1)
    gemm_mfma<false, false, true><<<dim3(8, 32, 4), blk, 0, stream>>>(
        attnb, C_, wprojt, C_, projP, nullptr, BT_, C_, 256);

    // x1 = LN(x + sa0+sa1+sa2+sa3 + bproj)
    ln_fused<true, 4><<<BT_, blk, 0, stream>>>(
        x, projP, projP + (long)BT_ * C_, projP + 2L * (long)BT_ * C_,
        projP + 3L * (long)BT_ * C_, bproj, ln1g, ln1b, x1f, x1b);

    // h = relu(x1 @ w1 + b1): 8-phase, 256 tiles
    gemm256_8ph<true, true, 1><<<dim3(256), dim3(512), 0, stream>>>(
        x1b, C_, w1t, C_, hb, b1, BT_, FF_, C_);

    // ff partials: 8-phase, split-K=4
    gemm256_8ph<false, false, 4><<<dim3(256), dim3(512), 0, stream>>>(
        hb, FF_, w2t, FF_, ffP, nullptr, BT_, C_, 1024);

    // out = LN(x1 + ff0+ff1+ff2+ff3 + b2)
    ln_fused<false, 4><<<BT_, blk, 0, stream>>>(
        x1f, ffP, ffP + (long)BT_ * C_, ffP + 2L * (long)BT_ * C_, ffP + 3L * (long)BT_ * C_,
        b2, ln2g, ln2b, out, nullptr);
}

// Round 21
// 221.989 us; speedup vs baseline: 1.0210x; 1.0210x over previous
//
#include <hip/hip_runtime.h>

#define B_  2
#define T_  2048
#define C_  1024
#define H_  16
#define HS_ 64
#define FF_ 4096
#define BT_ 4096
#define LDQKV 3072

typedef __bf16 bf16x8 __attribute__((ext_vector_type(8)));
typedef float f32x4 __attribute__((ext_vector_type(4)));

// Native f32->bf16 (RNE, single hardware cvt)
__device__ __forceinline__ unsigned short f2bf(float f) {
    union { __bf16 h; unsigned short u; } cv;
    cv.h = (__bf16)f;
    return cv.u;
}
__device__ __forceinline__ float bf2f(unsigned short b) {
    return __uint_as_float(((unsigned int)b) << 16);
}
// raw 2^x (v_exp_f32)
__device__ __forceinline__ float fexp2(float x) {
    float r;
    asm("v_exp_f32 %0, %1" : "=v"(r) : "v"(x));
    return r;
}
#define EXP_SCALE 0.18033688011112042f   // 0.125 * log2(e)

__device__ __forceinline__ void gload16(const void* g, void* l) {
    __builtin_amdgcn_global_load_lds(
        (const __attribute__((address_space(1))) void*)g,
        (__attribute__((address_space(3))) void*)l, 16, 0, 0);
}

// ---------------------------------------------------------------------------
// Tiled transpose + f32->bf16. out[n*K + k] = in[(n>>6)*b_os + k*ldb + (n&63)]
// ---------------------------------------------------------------------------
__global__ __launch_bounds__(256) void transpose_bf16(
    const float* __restrict__ in, int ldb, long b_os,
    unsigned short* __restrict__ out, int K, int N)
{
    __shared__ float t[32][33];
    const int k0 = blockIdx.x * 32, n0 = blockIdx.y * 32;
    const int tx = threadIdx.x & 31, ty = threadIdx.x >> 5;
    #pragma unroll
    for (int i = 0; i < 4; i++) {
        int k = k0 + ty + i * 8;
        int n = n0 + tx;
        t[ty + i * 8][tx] = in[(long)(n >> 6) * b_os + (long)k * ldb + (n & 63)];
    }
    __syncthreads();
    #pragma unroll
    for (int i = 0; i < 4; i++) {
        int n = n0 + ty + i * 8;
        out[(long)n * K + k0 + tx] = f2bf(t[tx][ty + i * 8]);
    }
}

// Merged QKV weight transpose: z selects wq/wk/wv (head-blocked (H,C,HS)).
__global__ __launch_bounds__(256) void transpose_qkv_bf16(
    const float* __restrict__ wq, const float* __restrict__ wk,
    const float* __restrict__ wv, unsigned short* __restrict__ out)
{
    __shared__ float t[32][33];
    const float* in = (blockIdx.z == 0) ? wq : (blockIdx.z == 1) ? wk : wv;
    unsigned short* o = out + (long)blockIdx.z * C_ * C_;
    const int k0 = blockIdx.x * 32, n0 = blockIdx.y * 32;
    const int tx = threadIdx.x & 31, ty = threadIdx.x >> 5;
    #pragma unroll
    for (int i = 0; i < 4; i++) {
        int k = k0 + ty + i * 8;
        int n = n0 + tx;
        t[ty + i * 8][tx] = in[(long)(n >> 6) * ((long)C_ * HS_) + (long)k * HS_ + (n & 63)];
    }
    __syncthreads();
    #pragma unroll
    for (int i = 0; i < 4; i++) {
        int n = n0 + ty + i * 8;
        o[(long)n * C_ + k0 + tx] = f2bf(t[tx][ty + i * 8]);
    }
}

__global__ __launch_bounds__(256) void convert_bf16_k(
    const float* __restrict__ in, unsigned short* __restrict__ out)
{
    int i = blockIdx.x * 256 + threadIdx.x;
    float4 v = ((const float4*)in)[i];
    ushort4 o;
    o.x = f2bf(v.x); o.y = f2bf(v.y); o.z = f2bf(v.z); o.w = f2bf(v.w);
    ((ushort4*)out)[i] = o;
}

// ---------------------------------------------------------------------------
// bf16 MFMA GEMM (round-13 proven): m97 tile + XCD supertile swizzle +
// 2-phase dbuf K-loop. Used for QKV / proj.
// ---------------------------------------------------------------------------
template<bool RELU, bool BIAS, bool OUT_BF16>
__global__ __launch_bounds__(256) void gemm_mfma(
    const unsigned short* __restrict__ A, int lda,
    const unsigned short* __restrict__ Bt, int ldb,
    void* __restrict__ Cc, const float* __restrict__ bias,
    int M, int N, int Ksub)
{
    __shared__ __align__(16) unsigned short As[2][128 * 32];
    __shared__ __align__(16) unsigned short Bs[2][128 * 32];
    const int tid = threadIdx.x;
    const int w = tid >> 6, l = tid & 63;
    const int fr = l & 15, fq = l >> 4;

    const int gx = gridDim.x;
    const int total = gx * gridDim.y;
    const int bid = blockIdx.y * gx + blockIdx.x;
    const int v = (bid & 7) * (total >> 3) + (bid >> 3);
    const int sw8 = gx << 3;
    const int r = v % sw8;
    const int mt = ((v / sw8) << 3) + (r & 7);
    const int nt = r >> 3;
    const int m0 = mt * 128, n0 = nt * 128;

    const int wm = (w >> 1) * 64, wn = (w & 1) * 64;
    const int kz = blockIdx.z;
    A  += (long)kz * Ksub;
    Bt += (long)kz * Ksub;

    f32x4 acc[4][4];
    #pragma unroll
    for (int m = 0; m < 4; m++)
        #pragma unroll
        for (int n = 0; n < 4; n++) acc[m][n] = (f32x4){0.f, 0.f, 0.f, 0.f};

    const int s0 = w * 64 + l;
    const int s1 = 256 + s0;
    const int nkt = Ksub >> 5;

    {
        gload16(&A[(long)(m0 + (s0 >> 2)) * lda + (s0 & 3) * 8], &As[0][s0 * 8]);
        gload16(&Bt[(long)(n0 + (s0 >> 2)) * ldb + (s0 & 3) * 8], &Bs[0][s0 * 8]);
        gload16(&A[(long)(m0 + (s1 >> 2)) * lda + (s1 & 3) * 8], &As[0][s1 * 8]);
        gload16(&Bt[(long)(n0 + (s1 >> 2)) * ldb + (s1 & 3) * 8], &Bs[0][s1 * 8]);
    }
    __syncthreads();

    for (int kt = 0; kt < nkt; kt++) {
        const int cur = kt & 1;
        const int nxt = cur ^ 1;

        if (kt + 1 < nkt) {
            const int k0 = (kt + 1) * 32;
            gload16(&A[(long)(m0 + (s0 >> 2)) * lda + k0 + (s0 & 3) * 8], &As[nxt][s0 * 8]);
            gload16(&Bt[(long)(n0 + (s0 >> 2)) * ldb + k0 + (s0 & 3) * 8], &Bs[nxt][s0 * 8]);
            gload16(&A[(long)(m0 + (s1 >> 2)) * lda + k0 + (s1 & 3) * 8], &As[nxt][s1 * 8]);
            gload16(&Bt[(long)(n0 + (s1 >> 2)) * ldb + k0 + (s1 & 3) * 8], &Bs[nxt][s1 * 8]);
        }

        bf16x8 a[4], b[4];
        #pragma unroll
        for (int m = 0; m < 4; m++)
            a[m] = *(const bf16x8*)&As[cur][(wm + m * 16 + fr) * 32 + fq * 8];
        #pragma unroll
        for (int n = 0; n < 4; n++)
            b[n] = *(const bf16x8*)&Bs[cur][(wn + n * 16 + fr) * 32 + fq * 8];
        __builtin_amdgcn_s_setprio(1);
        #pragma unroll
        for (int m = 0; m < 4; m++)
            #pragma unroll
            for (int n = 0; n < 4; n++)
                acc[m][n] = __builtin_amdgcn_mfma_f32_16x16x32_bf16(
                    a[m], b[n], acc[m][n], 0, 0, 0);
        __builtin_amdgcn_s_setprio(0);

        __syncthreads();
    }

    const long obase = (long)kz * M * N;
    #pragma unroll
    for (int m = 0; m < 4; m++) {
        #pragma unroll
        for (int n = 0; n < 4; n++) {
            int col = n0 + wn + n * 16 + fr;
            float bv = BIAS ? bias[col] : 0.f;
            #pragma unroll
            for (int j = 0; j < 4; j++) {
                long row = m0 + wm + m * 16 + fq * 4 + j;
                float v2 = acc[m][n][j] + bv;
                if (RELU) v2 = fmaxf(v2, 0.f);
                if (OUT_BF16) ((unsigned short*)Cc)[obase + row * N + col] = f2bf(v2);
                else          ((float*)Cc)[obase + row * N + col] = v2;
            }
        }
    }
}

// ---------------------------------------------------------------------------
// 256x256 8-phase GEMM (T2+T3+T4 template) with KSPLIT split-K.
// FFN1: KSPLIT=1, 256 tiles. FFN2: KSPLIT=4, Ksub=1024, 64x4=256 blocks.
// Swizzle: k-seg' = seg ^ ((row>>1)&3) on BOTH gload source and ds_read
// (2-way banks, free). Counted vmcnt(8), never 0 in steady state.
// ---------------------------------------------------------------------------
template<bool RELU, bool BIAS, int KSPLIT>
__global__ __launch_bounds__(512) void gemm256_8ph(
    const unsigned short* __restrict__ A, int lda,
    const unsigned short* __restrict__ Bt, int ldb,
    unsigned short* __restrict__ Cc, const float* __restrict__ bias,
    int M, int N, int Ksub)
{
    __shared__ __align__(16) unsigned short As[2][2][256 * 32];
    __shared__ __align__(16) unsigned short Bs[2][2][256 * 32];
    const int tid = threadIdx.x;
    const int w = tid >> 6, l = tid & 63;
    const int fr = l & 15, fq = l >> 4;
    const int rl = l >> 2, sg = l & 3;
    const int swl = (sg ^ ((rl >> 1) & 3)) * 8;   // pre-swizzled k-offset

    const int ntn = N >> 8;
    const int ntiles = (M >> 8) * ntn;
    const int total = ntiles * KSPLIT;
    const int bid = blockIdx.x;
    const int v = (bid & 7) * (total >> 3) + (bid >> 3);
    const int kz = v / ntiles;
    const int tl = v % ntiles;
    const int mt = tl / ntn, nt = tl % ntn;
    const int m0 = mt << 8, n0 = nt << 8;
    A  += (long)kz * Ksub;
    Bt += (long)kz * Ksub;

    const int wrow = (w >> 2) * 128;
    const int wcol = (w & 3) * 64;

    f32x4 acc[8][4];
    #pragma unroll
    for (int m = 0; m < 8; m++)
        #pragma unroll
        for (int n = 0; n < 4; n++) acc[m][n] = (f32x4){0.f, 0.f, 0.f, 0.f};

    const int nkt = Ksub >> 6;   // K-tiles of 64 (>= 2)

#define STG256(P_, ld_, rb0_, blk_, t_, kk_) do {                             \
        _Pragma("unroll")                                                     \
        for (int i_ = 0; i_ < 2; i_++) {                                      \
            int u_ = w + i_ * 8;                                              \
            int R_ = u_ * 16 + rl;                                            \
            gload16(&(P_)[(long)((rb0_) + R_) * (ld_) + (t_) * 64 + (kk_) * 32 + swl], \
                    &(blk_)[u_ * 512 + l * 8]);                               \
        }                                                                     \
    } while (0)

#define PHASE256(d_, kk_, mh_) do {                                           \
        bf16x8 a_[4], b_[4];                                                  \
        _Pragma("unroll")                                                     \
        for (int m_ = 0; m_ < 4; m_++) {                                      \
            int R_ = wrow + (mh_) * 64 + m_ * 16 + fr;                        \
            a_[m_] = *(const bf16x8*)&As[d_][kk_][R_ * 32 + (fq ^ ((R_ >> 1) & 3)) * 8]; \
        }                                                                     \
        _Pragma("unroll")                                                     \
        for (int n_ = 0; n_ < 4; n_++) {                                      \
            int R_ = wcol + n_ * 16 + fr;                                     \
            b_[n_] = *(const bf16x8*)&Bs[d_][kk_][R_ * 32 + (fq ^ ((R_ >> 1) & 3)) * 8]; \
        }                                                                     \
        __builtin_amdgcn_s_setprio(1);                                        \
        _Pragma("unroll")                                                     \
        for (int m_ = 0; m_ < 4; m_++)                                        \
            _Pragma("unroll")                                                 \
            for (int n_ = 0; n_ < 4; n_++)                                    \
                acc[(mh_) * 4 + m_][n_] = __builtin_amdgcn_mfma_f32_16x16x32_bf16( \
                    a_[m_], b_[n_], acc[(mh_) * 4 + m_][n_], 0, 0, 0);        \
        __builtin_amdgcn_s_setprio(0);                                        \
    } while (0)

    STG256(A, lda, m0, As[0][0], 0, 0);
    STG256(Bt, ldb, n0, Bs[0][0], 0, 0);
    STG256(A, lda, m0, As[0][1], 0, 1);
    STG256(Bt, ldb, n0, Bs[0][1], 0, 1);
    STG256(A, lda, m0, As[1][0], 1, 0);
    STG256(Bt, ldb, n0, Bs[1][0], 1, 0);
    asm volatile("s_waitcnt vmcnt(8)" ::: "memory");
    __builtin_amdgcn_s_barrier();

    for (int t = 0; t < nkt; t++) {
        const int d = t & 1;

        if (t + 1 < nkt) STG256(A, lda, m0, As[d ^ 1][1], t + 1, 1);
        PHASE256(d, 0, 0);
        if (t + 1 < nkt) STG256(Bt, ldb, n0, Bs[d ^ 1][1], t + 1, 1);
        PHASE256(d, 0, 1);

        if (t + 1 < nkt) asm volatile("s_waitcnt vmcnt(8)" ::: "memory");
        else             asm volatile("s_waitcnt vmcnt(0)" ::: "memory");
        __builtin_amdgcn_s_barrier();

        if (t + 2 < nkt) STG256(A, lda, m0, As[d][0], t + 2, 0);
        PHASE256(d, 1, 0);
        if (t + 2 < nkt) STG256(Bt, ldb, n0, Bs[d][0], t + 2, 0);
        PHASE256(d, 1, 1);

        if (t + 1 < nkt) {
            if (t + 2 < nkt) asm volatile("s_waitcnt vmcnt(8)" ::: "memory");
            else             asm volatile("s_waitcnt vmcnt(4)" ::: "memory");
            __builtin_amdgcn_s_barrier();
        }
    }
#undef STG256
#undef PHASE256

    const long obase = (long)kz * M * N;
    #pragma unroll
    for (int mi = 0; mi < 8; mi++) {
        #pragma unroll
        for (int n = 0; n < 4; n++) {
            int col = n0 + wcol + n * 16 + fr;
            float bv = BIAS ? bias[col] : 0.f;
            #pragma unroll
            for (int j = 0; j < 4; j++) {
                long row = m0 + wrow + (mi >> 2) * 64 + (mi & 3) * 16 + fq * 4 + j;
                float vv = acc[mi][n][j] + bv;
                if (RELU) vv = fmaxf(vv, 0.f);
                Cc[obase + row * N + col] = f2bf(vv);
            }
        }
    }
}

// ---------------------------------------------------------------------------
// MFMA flash attention: 8 waves x 16 q-rows, CU-balanced 1D grid, K/V dbuf,
// V-store swizzle, masked-tile skip, max-free softmax (native bf16 cvt,
// single v_exp_f32, wave-uniform mask skip), MFMA l-sum.
// ---------------------------------------------------------------------------
__global__ __launch_bounds__(512) void attn_mfma(
    const unsigned short* __restrict__ qkv, unsigned short* __restrict__ ob)
{
    const int bid = blockIdx.x;
    const int i4  = bid & 255;
    const int b   = bid >> 8;
    const int j4  = i4 >> 4;
    const int h   = i4 & 15;
    const int qt  = b ? (15 - j4) : j4;
    const int tid = threadIdx.x;
    const int w = tid >> 6, l = tid & 63;
    const int fr = l & 15, fq = l >> 4;

    __shared__ __align__(16) unsigned short Ks[2][64 * 64];
    __shared__ __align__(16) unsigned short Vt[2][64 * 72];
    __shared__ __align__(16) unsigned short Ps[8][16 * 72];

    const long qrow = (long)(b * T_ + qt * 128 + w * 16 + fr);
    const bf16x8 qf0 = *(const bf16x8*)&qkv[qrow * LDQKV + h * 64 + fq * 8];
    const bf16x8 qf1 = *(const bf16x8*)&qkv[qrow * LDQKV + h * 64 + 32 + fq * 8];

    const bf16x8 ones = {(__bf16)1.f, (__bf16)1.f, (__bf16)1.f, (__bf16)1.f,
                         (__bf16)1.f, (__bf16)1.f, (__bf16)1.f, (__bf16)1.f};

    const int kr  = tid >> 3;
    const int keo = ((tid & 7) ^ (kr & 7)) * 8;
    const int vr  = tid >> 3;
    const int vc  = (tid & 7) * 8;
    const int vrs = vr ^ ((tid & 7) << 3);

    f32x4 oacc[4];
    f32x4 lacc = (f32x4){0.f, 0.f, 0.f, 0.f};
    #pragma unroll
    for (int d = 0; d < 4; d++) oacc[d] = (f32x4){0.f, 0.f, 0.f, 0.f};

    const unsigned short* kb0 = qkv + (long)b * T_ * LDQKV + 1024 + h * 64;
    const unsigned short* vb0 = qkv + (long)b * T_ * LDQKV + 2048 + h * 64;

    const int qminw = qt * 128 + w * 16;
    const int qmaxw = qminw + 15;
    const int ntiles = qt * 2 + 2;

    gload16(kb0 + (long)kr * LDQKV + keo, &Ks[0][tid * 8]);
    {
        bf16x8 vv = *(const bf16x8*)&vb0[(long)vr * LDQKV + vc];
        #pragma unroll
        for (int jj = 0; jj < 8; jj++)
            Vt[0][(vc + jj) * 72 + vrs] = ((const unsigned short*)&vv)[jj];
    }
    __syncthreads();

    for (int st = 0; st < ntiles; st++) {
        const int cur = st & 1;
        const int nxt = cur ^ 1;

        bf16x8 vnext;
        if (st + 1 < ntiles) {
            const unsigned short* kb = kb0 + (long)(st + 1) * 64 * LDQKV;
            const unsigned short* vb = vb0 + (long)(st + 1) * 64 * LDQKV;
            gload16(kb + (long)kr * LDQKV + keo, &Ks[nxt][tid * 8]);
            vnext = *(const bf16x8*)&vb[(long)vr * LDQKV + vc];
        }

        const int sbase = st * 64;
        if (sbase <= qmaxw) {
            f32x4 sacc[4];
            {
                bf16x8 k0v[4], k1v[4];
                #pragma unroll
                for (int stile = 0; stile < 4; stile++) {
                    int krow = stile * 16 + fr;
                    int rb = krow * 128;
                    int sw = (krow & 7) << 4;
                    k0v[stile] = *(const bf16x8*)((const char*)Ks[cur] + rb + ((fq * 16) ^ sw));
                    k1v[stile] = *(const bf16x8*)((const char*)Ks[cur] + rb + ((64 + fq * 16) ^ sw));
                }
                __builtin_amdgcn_s_setprio(1);
                #pragma unroll
                for (int stile = 0; stile < 4; stile++) {
                    sacc[stile] = (f32x4){0.f, 0.f, 0.f, 0.f};
                    sacc[stile] = __builtin_amdgcn_mfma_f32_16x16x32_bf16(qf0, k0v[stile], sacc[stile], 0, 0, 0);
                    sacc[stile] = __builtin_amdgcn_mfma_f32_16x16x32_bf16(qf1, k1v[stile], sacc[stile], 0, 0, 0);
                }
                __builtin_amdgcn_s_setprio(0);
            }

            if (sbase + 63 <= qminw) {
                #pragma unroll
                for (int stile = 0; stile < 4; stile++)
                    #pragma unroll
                    for (int j = 0; j < 4; j++)
                        Ps[w][(fq * 4 + j) * 72 + stile * 16 + fr] =
                            f2bf(fexp2(sacc[stile][j] * EXP_SCALE));
            } else {
                const int qbase = qminw + fq * 4;
                #pragma unroll
                for (int stile = 0; stile < 4; stile++) {
                    #pragma unroll
                    for (int j = 0; j < 4; j++) {
                        float e = fexp2(sacc[stile][j] * EXP_SCALE);
                        if (sbase + stile * 16 + fr > qbase + j) e = 0.f;
                        Ps[w][(fq * 4 + j) * 72 + stile * 16 + fr] = f2bf(e);
                    }
                }
            }

            {
                bf16x8 pf0 = *(const bf16x8*)&Ps[w][fr * 72 + fq * 8];
                bf16x8 pf1 = *(const bf16x8*)&Ps[w][fr * 72 + 32 + fq * 8];
                __builtin_amdgcn_s_setprio(1);
                lacc = __builtin_amdgcn_mfma_f32_16x16x32_bf16(pf0, ones, lacc, 0, 0, 0);
                lacc = __builtin_amdgcn_mfma_f32_16x16x32_bf16(pf1, ones, lacc, 0, 0, 0);
                #pragma unroll
                for (int df = 0; df < 4; df++) {
                    int row = df * 16 + fr;
                    int c = (row >> 3) & 7;
                    bf16x8 v0 = *(const bf16x8*)&Vt[cur][row * 72 + ((fq ^ c) * 8)];
                    bf16x8 v1 = *(const bf16x8*)&Vt[cur][row * 72 + (((fq + 4) ^ c) * 8)];
                    oacc[df] = __builtin_amdgcn_mfma_f32_16x16x32_bf16(pf0, v0, oacc[df], 0, 0, 0);
                    oacc[df] = __builtin_amdgcn_mfma_f32_16x16x32_bf16(pf1, v1, oacc[df], 0, 0, 0);
                }
                __builtin_amdgcn_s_setprio(0);
            }
        }

        if (st + 1 < ntiles) {
            #pragma unroll
            for (int jj = 0; jj < 8; jj++)
                Vt[nxt][(vc + jj) * 72 + vrs] = ((const unsigned short*)&vnext)[jj];
        }

        __syncthreads();
    }

    #pragma unroll
    for (int j = 0; j < 4; j++) {
        float inv = 1.f / lacc[j];
        long orow = (long)(b * T_ + qt * 128 + w * 16 + fq * 4 + j);
        #pragma unroll
        for (int df = 0; df < 4; df++)
            ob[orow * C_ + h * 64 + df * 16 + fr] = f2bf(oacc[df][j] * inv);
    }
}

// ---------------------------------------------------------------------------
// Fused residual + NP-partial split-K merge + bias + LayerNorm
// ---------------------------------------------------------------------------
template<bool WB, int NP>
__global__ __launch_bounds__(256) void ln_fused(
    const float* __restrict__ a,
    const unsigned short* __restrict__ b0, const unsigned short* __restrict__ b1,
    const unsigned short* __restrict__ b2p, const unsigned short* __restrict__ b3p,
    const float* __restrict__ bias,
    const float* __restrict__ g, const float* __restrict__ be,
    float* __restrict__ outf, unsigned short* __restrict__ outb)
{
    const long row = blockIdx.x;
    const int tid = threadIdx.x;

    float4 av = ((const float4*)(a + row * C_))[tid];
    ushort4 b0v = ((const ushort4*)(b0 + row * C_))[tid];
    ushort4 b1v = ((const ushort4*)(b1 + row * C_))[tid];
    float4 biv = ((const float4*)bias)[tid];
    float v[4];
    v[0] = av.x + bf2f(b0v.x) + bf2f(b1v.x) + biv.x;
    v[1] = av.y + bf2f(b0v.y) + bf2f(b1v.y) + biv.y;
    v[2] = av.z + bf2f(b0v.z) + bf2f(b1v.z) + biv.z;
    v[3] = av.w + bf2f(b0v.w) + bf2f(b1v.w) + biv.w;
    if (NP == 4) {
        ushort4 b2v = ((const ushort4*)(b2p + row * C_))[tid];
        ushort4 b3v = ((const ushort4*)(b3p + row * C_))[tid];
        v[0] += bf2f(b2v.x) + bf2f(b3v.x);
        v[1] += bf2f(b2v.y) + bf2f(b3v.y);
        v[2] += bf2f(b2v.z) + bf2f(b3v.z);
        v[3] += bf2f(b2v.w) + bf2f(b3v.w);
    }

    float s = v[0] + v[1] + v[2] + v[3];
    #pragma unroll
    for (int off = 32; off > 0; off >>= 1) s += __shfl_down(s, off);
    __shared__ float red[4], red2[4];
    const int wid = tid >> 6, lane = tid & 63;
    if (lane == 0) red[wid] = s;
    __syncthreads();
    float mean = (red[0] + red[1] + red[2] + red[3]) * (1.f / 1024.f);

    float vs = 0.f;
    #pragma unroll
    for (int i = 0; i < 4; i++) { float d = v[i] - mean; vs += d * d; }
    #pragma unroll
    for (int off = 32; off > 0; off >>= 1) vs += __shfl_down(vs, off);
    if (lane == 0) red2[wid] = vs;
    __syncthreads();
    float var = (red2[0] + red2[1] + red2[2] + red2[3]) * (1.f / 1024.f);
    float rstd = rsqrtf(var + 1e-5f);

    float4 gv = ((const float4*)g)[tid];
    float4 ev = ((const float4*)be)[tid];
    float4 ov;
    ov.x = (v[0] - mean) * rstd * gv.x + ev.x;
    ov.y = (v[1] - mean) * rstd * gv.y + ev.y;
    ov.z = (v[2] - mean) * rstd * gv.z + ev.z;
    ov.w = (v[3] - mean) * rstd * gv.w + ev.w;
    ((float4*)(outf + row * C_))[tid] = ov;
    if (WB) {
        ushort4 o;
        o.x = f2bf(ov.x); o.y = f2bf(ov.y); o.z = f2bf(ov.z); o.w = f2bf(ov.w);
        ((ushort4*)(outb + row * C_))[tid] = o;
    }
}

// ---------------------------------------------------------------------------
// Workspace (MB), liveness-packed, peak 96:
//   [0,8)   xb   -> ffP0     [8,14) wqkvt -> ffP1[8,16)
//   [14,16) wprojt           [16,24) w1t -> ffP2
//   [24,32) free -> ffP3     [32,56) qkv -> saP[32,48) -> hb[32,64)
//   [56,64) attnb            [64,72) w2t
//   [72,88) x1f              [88,96) x1b
// ---------------------------------------------------------------------------
extern "C" void kernel_launch(void* const* d_in, const int* in_sizes, int n_in,
                              void* d_out, int out_size, void* d_ws, size_t ws_size,
                              hipStream_t stream) {
    const float* x     = (const float*)d_in[0];
    const float* wq    = (const float*)d_in[1];
    const float* wk    = (const float*)d_in[2];
    const float* wv    = (const float*)d_in[3];
    const float* wproj = (const float*)d_in[4];
    const float* bproj = (const float*)d_in[5];
    const float* ln1g  = (const float*)d_in[6];
    const float* ln1b  = (const float*)d_in[7];
    const float* w1    = (const float*)d_in[8];
    const float* b1    = (const float*)d_in[9];
    const float* w2    = (const float*)d_in[10];
    const float* b2    = (const float*)d_in[11];
    const float* ln2g  = (const float*)d_in[12];
    const float* ln2b  = (const float*)d_in[13];
    float* out = (float*)d_out;

    char* wsb = (char*)d_ws;
    unsigned short* xb     = (unsigned short*)(wsb);                 // [0,8)
    unsigned short* wqkvt  = (unsigned short*)(wsb + (8L  << 20));   // [8,14)
    unsigned short* wprojt = (unsigned short*)(wsb + (14L << 20));   // [14,16)
    unsigned short* w1t    = (unsigned short*)(wsb + (16L << 20));   // [16,24)
    unsigned short* w2t    = (unsigned short*)(wsb + (64L << 20));   // [64,72)
    unsigned short* qkv    = (unsigned short*)(wsb + (32L << 20));   // [32,56)
    unsigned short* attnb  = (unsigned short*)(wsb + (56L << 20));   // [56,64)
    unsigned short* saP    = (unsigned short*)(wsb + (32L << 20));   // [32,48)
    float*          x1f    = (float*)(wsb + (72L << 20));            // [72,88)
    unsigned short* x1b    = (unsigned short*)(wsb + (88L << 20));   // [88,96)
    unsigned short* hb     = (unsigned short*)(wsb + (32L << 20));   // [32,64)
    unsigned short* ffP    = (unsigned short*)(wsb);                 // [0,32)

    dim3 blk(256);

    convert_bf16_k<<<BT_ * C_ / 1024, blk, 0, stream>>>(x, xb);
    transpose_qkv_bf16<<<dim3(32, 32, 3), blk, 0, stream>>>(wq, wk, wv, wqkvt);
    transpose_bf16<<<dim3(32, 32),  blk, 0, stream>>>(wproj, C_,  64L, wprojt, C_, C_);
    transpose_bf16<<<dim3(32, 128), blk, 0, stream>>>(w1,    FF_, 64L, w1t,    C_, FF_);
    transpose_bf16<<<dim3(128, 32), blk, 0, stream>>>(w2,    C_,  64L, w2t,    FF_, C_);

    // fused QKV projection (2-phase)
    gemm_mfma<false, false, true><<<dim3(24, 32, 1), blk, 0, stream>>>(
        xb, C_, wqkvt, C_, qkv, nullptr, BT_, LDQKV, C_);

    // attention
    attn_mfma<<<dim3(512), dim3(512), 0, stream>>>(qkv, attnb);

    // output projection, split-K=2 (bias folded into LN1), 2-phase
    gemm_mfma<false, false, true><<<dim3(8, 32, 2), blk, 0, stream>>>(
        attnb, C_, wprojt, C_, saP, nullptr, BT_, C_, 512);

    // x1 = LN(x + sa0 + sa1 + bproj)
    ln_fused<true, 2><<<BT_, blk, 0, stream>>>(
        x, saP, saP + (long)BT_ * C_, nullptr, nullptr, bproj, ln1g, ln1b, x1f, x1b);

    // h = relu(x1 @ w1 + b1): 8-phase, 256 tiles
    gemm256_8ph<true, true, 1><<<dim3(256), dim3(512), 0, stream>>>(
        x1b, C_, w1t, C_, hb, b1, BT_, FF_, C_);

    // ff partials: 8-phase, split-K=4
    gemm256_8ph<false, false, 4><<<dim3(256), dim3(512), 0, stream>>>(
        hb, FF_, w2t, FF_, ffP, nullptr, BT_, C_, 1024);

    // out = LN(x1 + ff0+ff1+ff2+ff3 + b2)
    ln_fused<false, 4><<<BT_, blk, 0, stream>>>(
        x1f, ffP, ffP + (long)BT_ * C_, ffP + 2L * (long)BT_ * C_, ffP + 3L * (long)BT_ * C_,
        b2, ln2g, ln2b, out, nullptr);
}